// Round 7
// baseline (114.917 us; speedup 1.0000x reference)
//
#include <hip/hip_runtime.h>
#include <math.h>

#define N_TOT 8400
#define MASK_WORDS 132   // ceil(8400/64)
#define CAP 32           // max far (word,bits) entries per row
#define RT 33            // rank tiles: ceil(8400/256)
#define NBP 256          // pairs blocks

typedef unsigned long long u64;

// monotone-increasing float->u32 mapping
__device__ __forceinline__ unsigned mono_u32(float f) {
    unsigned u = __float_as_uint(f);
    return (u & 0x80000000u) ? ~u : (u | 0x80000000u);
}

// workspace layout (byte offsets, 16B aligned)
#define WS_SLOGIT  0         // 8400*4  = 33600
#define WS_SBOX    33600     // 8400*16 = 134400
#define WS_CNT     168000    // 8400*4  = 33600
#define WS_ROWFLAG 201600    // 132*8 = 1056 (+pad)
#define WS_DIAG    202672    // 8448*8  = 67584
#define WS_ENT     270256    // 8400*32*16 = 4300800
#define WS_PARTIAL 4571056   // 33*8448*4 = 1115136

// ---------------- K1: tiled rank partials, keys computed inline from scores ----------------
// Block (bi,bj): rank contribution of j-tile bj to the 256 elements of i-tile bi.
// Keys are u64 (~mono(logit))<<14 | index  ->  ascending key == descending logit with
// ascending-index tie-break.  Plain store to partial[bj][i]: no atomics, no init kernel.
__global__ __launch_bounds__(256) void rank_partial_kernel(
        const float* __restrict__ score0, const float* __restrict__ score1,
        const float* __restrict__ score2, int* __restrict__ partial) {
    __shared__ u64 tile[256];
    const int tid = threadIdx.x;
    const int bi = blockIdx.x, bj = blockIdx.y;

    int j = bj * 256 + tid;
    u64 kj = ~0ull;                           // OOB sorts last (never < ki)
    if (j < N_TOT) {
        const float* sc; int m;
        if (j < 6400)      { sc = score0; m = j; }
        else if (j < 8000) { sc = score1; m = j - 6400; }
        else               { sc = score2; m = j - 8000; }
        kj = ((u64)(~mono_u32(sc[m])) << 14) | (u64)j;
    }
    tile[tid] = kj;
    __syncthreads();

    int i = bi * 256 + tid;
    if (i >= N_TOT) return;
    const float* sc; int m;
    if (i < 6400)      { sc = score0; m = i; }
    else if (i < 8000) { sc = score1; m = i - 6400; }
    else               { sc = score2; m = i - 8000; }
    u64 ki = ((u64)(~mono_u32(sc[m])) << 14) | (u64)i;
    int rk = 0;
    #pragma unroll 8
    for (int k = 0; k < 256; ++k) rk += (tile[k] < ki) ? 1 : 0;
    partial[bj * 8448 + i] = rk;
}

// ---------------- K2: rank-sum + decode + sorted scatter + pre-masked outputs ----------------
// Absorbs old decode/scatter/output kernels: writes sorted working arrays for pairs AND
// the final outputs pre-masked by valid (lg>0).  NMS tail later zeroes suppressed rows.
// Also zero-inits cnt/rowflag for the pairs kernel (kernel boundary orders it).
__global__ __launch_bounds__(256) void decode_scatter_kernel(
        const float* __restrict__ score0, const float* __restrict__ bbox0, const float* __restrict__ kps0,
        const float* __restrict__ score1, const float* __restrict__ bbox1, const float* __restrict__ kps1,
        const float* __restrict__ score2, const float* __restrict__ bbox2, const float* __restrict__ kps2,
        const int* __restrict__ partial,
        float* __restrict__ s_logit, float* __restrict__ s_box,
        unsigned* __restrict__ cnt, u64* __restrict__ rowflag,
        float* __restrict__ out) {
    int i = blockIdx.x * 256 + threadIdx.x;
    if (i < N_TOT) cnt[i] = 0u;
    if (i < MASK_WORDS) rowflag[i] = 0ull;
    if (i >= N_TOT) return;

    int r = 0;
    #pragma unroll
    for (int b = 0; b < RT; ++b) r += partial[b * 8448 + i];   // coalesced per b

    const float *sc, *bb, *kp; int m, F; float s;
    if (i < 6400)      { sc=score0; bb=bbox0; kp=kps0; m=i;       F=80; s=8.f;  }
    else if (i < 8000) { sc=score1; bb=bbox1; kp=kps1; m=i-6400;  F=40; s=16.f; }
    else               { sc=score2; bb=bbox2; kp=kps2; m=i-8000;  F=20; s=32.f; }
    float px = (float)(m % F) * s;
    float py = (float)(m / F) * s;
    float lg = sc[m];
    float mv = (lg > 0.f) ? 1.f : 0.f;
    s_logit[r] = lg;
    float d0=bb[m*4+0]*s, d1=bb[m*4+1]*s, d2=bb[m*4+2]*s, d3=bb[m*4+3]*s;
    float x1 = px - d0, y1 = py - d1, x2 = px + d2, y2 = py + d3;
    ((float4*)s_box)[r] = make_float4(x1, y1, x2, y2);

    float* ob  = out;            // 8400*4
    float* os  = out + 33600;    // 8400
    float* okp = out + 42000;    // 8400*10
    float* om  = out + 126000;   // 8400
    ob[r*4+0]=x1*mv; ob[r*4+1]=y1*mv; ob[r*4+2]=x2*mv; ob[r*4+3]=y2*mv;
    os[r] = (1.0f / (1.0f + expf(-lg))) * mv;
    #pragma unroll
    for (int c = 0; c < 5; ++c) {
        okp[r*10 + 2*c]   = (px + kp[m*10 + 2*c]   * s) * mv;
        okp[r*10 + 2*c+1] = (py + kp[m*10 + 2*c+1] * s) * mv;
    }
    om[r] = mv;    // provisional; NMS tail zeroes suppressed rows
}

// ---------------- K3: triangular pairs (wave-task loop); diag channel + far ent[] ----------------
__global__ __launch_bounds__(256) void pairs_kernel(
        const float* __restrict__ s_logit, const float* __restrict__ s_box,
        unsigned* __restrict__ cnt, ulonglong2* __restrict__ ent,
        u64* __restrict__ diag, u64* __restrict__ rowflag) {
    __shared__ float4 cboxS[4][64];
    __shared__ float  careaS[4][64];
    const int tid = threadIdx.x;
    const int wv = tid >> 6, lane = tid & 63;
    const int gw = blockIdx.x * 4 + wv;

    for (int t = gw; t < 132 * 67; t += NBP * 4) {
        int x = t % 132, y = t / 132;
        int rb, cw;
        if (x + y < MASK_WORDS) { rb = x; cw = x + y; }
        else if (y == MASK_WORDS / 2) continue;      // wrapped y=66 duplicates direct
        else { rb = x + y - MASK_WORDS; cw = x; }
        bool isdiag = (rb == cw);

        int j = cw * 64 + lane;
        float4 cb = make_float4(0.f, 0.f, 0.f, 0.f);
        float lgj = -1.f;
        if (j < N_TOT) {
            cb = ((const float4*)s_box)[j];
            lgj = s_logit[j];
        }
        cboxS[wv][lane] = cb;              // wave-local LDS: in-order, no barrier
        careaS[wv][lane] = (cb.z - cb.x) * (cb.w - cb.y);
        u64 cvalid = __ballot(j < N_TOT && lgj > 0.f);
        if (!isdiag && cvalid == 0ull) continue;     // sorted => no valid cols here

        int r = rb * 64 + lane;
        float lgr = isdiag ? lgj : ((r < N_TOT) ? s_logit[r] : -1.f);
        if (!isdiag && __ballot(lgr > 0.f) == 0ull) continue;

        u64 bits = 0ull;
        if (cvalid != 0ull && lgr > 0.f) {
            float4 rb4 = isdiag ? cb : ((const float4*)s_box)[r];
            float rarea = (rb4.z - rb4.x) * (rb4.w - rb4.y);
            #pragma unroll 4
            for (int k = 0; k < 64; ++k) {
                float4 c4 = cboxS[wv][k];
                float ltx = fmaxf(rb4.x, c4.x);
                float lty = fmaxf(rb4.y, c4.y);
                float rbx = fminf(rb4.z, c4.z);
                float rby = fminf(rb4.w, c4.w);
                float w = fmaxf(rbx - ltx, 0.f);
                float h = fmaxf(rby - lty, 0.f);
                float inter = w * h;
                float iou = inter / (rarea + careaS[wv][k] - inter + 1e-9f);
                bits |= (iou > 0.4f) ? (1ull << k) : 0ull;
            }
            u64 m = cvalid;
            if (isdiag) m &= (lane == 63) ? 0ull : (~0ull << (lane + 1));
            bits &= m;
        }
        if (isdiag) {
            if (r < N_TOT) diag[r] = bits;           // unconditional (incl. zero)
            if (bits) atomicOr(&rowflag[r >> 6], 1ull << (r & 63));
            continue;
        }
        if (bits) {
            unsigned idx = atomicAdd(&cnt[r], 1u);
            if (idx < CAP) {
                ulonglong2 e; e.x = bits; e.y = (u64)cw;
                ent[(size_t)r * CAP + idx] = e;
            }
            atomicOr(&rowflag[r >> 6], 1ull << (r & 63));
        }
    }
}

// ---------------- K4: word-serial greedy resolve (wave 0) + zero suppressed outputs ----------------
__global__ __launch_bounds__(256) void nms_kernel(
        const u64* __restrict__ rowflag_g,
        const unsigned* __restrict__ cnt_g,
        const u64* __restrict__ diag_g,
        const ulonglong2* __restrict__ ent_g,
        float* __restrict__ out) {
    __shared__ u64 rem_lds[MASK_WORDS];
    __shared__ unsigned short wlist[MASK_WORDS];
    const int tid = threadIdx.x;

    for (int q = tid; q < MASK_WORDS; q += 256) rem_lds[q] = 0ull;
    __syncthreads();

    if (tid < 64) {
        int lane = tid;
        u64 rf[3];
        #pragma unroll
        for (int s = 0; s < 3; ++s) {
            int w = s * 64 + lane;
            rf[s] = (w < MASK_WORDS) ? rowflag_g[w] : 0ull;
        }
        int base = 0;
        #pragma unroll
        for (int s = 0; s < 3; ++s) {
            bool nz = rf[s] != 0ull;
            u64 bal = __ballot(nz);
            int pos = __popcll(bal & ((1ull << lane) - 1ull));
            if (nz) wlist[base + pos] = (unsigned short)(s * 64 + lane);
            base += (int)__popcll(bal);
        }
        int n_w = base;

        int wdA=0, wdB=0, wdC=0;
        unsigned cA=0u, cB=0u, cC=0u;
        u64 lbA=0ull, lbB=0ull, lbC=0ull;
        ulonglong2 A0,A1,A2,A3, B0,B1,B2,B3, C0,C1,C2,C3;
        A0.x=A0.y=0ull; A1=A0; A2=A0; A3=A0;
        B0=A0; B1=A0; B2=A0; B3=A0; C0=A0; C1=A0; C2=A0; C3=A0;

#define LOADST(t, wd, c, lb, e0, e1, e2, e3) do {              \
        wd = 0; c = 0u; lb = 0ull;                             \
        if ((t) < n_w) {                                       \
            wd = (int)wlist[t];                                \
            int row_ = wd * 64 + lane;                         \
            if (row_ < N_TOT) {                                \
                const ulonglong2* ep_ = ent_g + (size_t)row_ * CAP; \
                c  = cnt_g[row_];                              \
                lb = diag_g[row_];                             \
                e0 = ep_[0];                                   \
                e1 = ep_[1];                                   \
                e2 = ep_[2];                                   \
                e3 = ep_[3];                                   \
            }                                                  \
        }                                                      \
    } while (0)

#define STEP(wd, c, lb, e0, e1, e2, e3, TNEXT) do {            \
        u64 remw = rem_lds[wd];                                \
        u64 cand = __ballot(c > 0u || lb != 0ull) & ~remw;     \
        if (cand) {                                            \
            u64 kept;                                          \
            u64 S = __ballot(lb != 0ull) & cand;               \
            if (S == 0ull) {                                   \
                kept = cand;                                   \
            } else {                                           \
                u64 rn = remw;                                 \
                u64 pend = S;                                  \
                while (pend) {                                 \
                    int b_ = __builtin_ctzll(pend);            \
                    pend &= pend - 1ull;                       \
                    if (!((rn >> b_) & 1ull)) {                \
                        unsigned lo_ = (unsigned)__builtin_amdgcn_readlane((int)(unsigned)lb, b_); \
                        unsigned hi_ = (unsigned)__builtin_amdgcn_readlane((int)(unsigned)(lb >> 32), b_); \
                        rn |= ((u64)hi_ << 32) | (u64)lo_;     \
                        pend &= ~rn;                           \
                    }                                          \
                }                                              \
                kept = cand & ~rn;                             \
                if (lane == 0) rem_lds[wd] = rn;               \
            }                                                  \
            bool kp_ = (kept >> lane) & 1ull;                  \
            if (kp_) {                                         \
                if (c > 0u) atomicOr(&rem_lds[(int)e0.y], e0.x); \
                if (c > 1u) atomicOr(&rem_lds[(int)e1.y], e1.x); \
                if (c > 2u) atomicOr(&rem_lds[(int)e2.y], e2.x); \
                if (c > 3u) atomicOr(&rem_lds[(int)e3.y], e3.x); \
            }                                                  \
            if (__ballot(kp_ && c > 4u)) {                     \
                if (kp_ && c > 4u) {                           \
                    unsigned cm_ = min(c, (unsigned)CAP);      \
                    int row_ = wd * 64 + lane;                 \
                    for (unsigned e_ = 4; e_ < cm_; ++e_) {    \
                        ulonglong2 g_ = ent_g[(size_t)row_ * CAP + e_]; \
                        atomicOr(&rem_lds[(int)g_.y], g_.x);   \
                    }                                          \
                }                                              \
            }                                                  \
        }                                                      \
        LOADST(TNEXT, wd, c, lb, e0, e1, e2, e3);              \
    } while (0)

        if (n_w > 0) {
            LOADST(0, wdA, cA, lbA, A0, A1, A2, A3);
            LOADST(1, wdB, cB, lbB, B0, B1, B2, B3);
            LOADST(2, wdC, cC, lbC, C0, C1, C2, C3);
            int t = 0;
            while (true) {
                STEP(wdA, cA, lbA, A0, A1, A2, A3, t + 3); if (++t >= n_w) break;
                STEP(wdB, cB, lbB, B0, B1, B2, B3, t + 3); if (++t >= n_w) break;
                STEP(wdC, cC, lbC, C0, C1, C2, C3, t + 3); if (++t >= n_w) break;
            }
        }
#undef STEP
#undef LOADST
    }
    __syncthreads();

    // zero only suppressed rows (rem ⊆ valid by construction; everything else already correct)
    float* ob  = out;            // 8400*4
    float* os  = out + 33600;    // 8400
    float* okp = out + 42000;    // 8400*10
    float* om  = out + 126000;   // 8400
    for (int r = tid; r < N_TOT; r += 256) {
        if ((rem_lds[r >> 6] >> (r & 63)) & 1ull) {
            om[r] = 0.f;
            os[r] = 0.f;
            ((float4*)ob)[r] = make_float4(0.f, 0.f, 0.f, 0.f);
            #pragma unroll
            for (int c = 0; c < 10; ++c) okp[r*10 + c] = 0.f;
        }
    }
}

extern "C" void kernel_launch(void* const* d_in, const int* in_sizes, int n_in,
                              void* d_out, int out_size, void* d_ws, size_t ws_size,
                              hipStream_t stream) {
    const float *score0, *bbox0, *kps0, *score1, *bbox1, *kps1, *score2, *bbox2, *kps2;
    if (in_sizes[1] == 25600) {
        score0 = (const float*)d_in[0]; bbox0 = (const float*)d_in[1]; kps0 = (const float*)d_in[2];
        score1 = (const float*)d_in[3]; bbox1 = (const float*)d_in[4]; kps1 = (const float*)d_in[5];
        score2 = (const float*)d_in[6]; bbox2 = (const float*)d_in[7]; kps2 = (const float*)d_in[8];
    } else {
        score0 = (const float*)d_in[0]; score1 = (const float*)d_in[1]; score2 = (const float*)d_in[2];
        bbox0  = (const float*)d_in[3]; bbox1  = (const float*)d_in[4]; bbox2  = (const float*)d_in[5];
        kps0   = (const float*)d_in[6]; kps1   = (const float*)d_in[7]; kps2   = (const float*)d_in[8];
    }

    char* ws = (char*)d_ws;
    float* s_logit   = (float*)(ws + WS_SLOGIT);
    float* s_box     = (float*)(ws + WS_SBOX);
    unsigned* cnt    = (unsigned*)(ws + WS_CNT);
    u64* rowflag     = (u64*)(ws + WS_ROWFLAG);
    u64* diag        = (u64*)(ws + WS_DIAG);
    ulonglong2* ent  = (ulonglong2*)(ws + WS_ENT);
    int* partial     = (int*)(ws + WS_PARTIAL);
    float* out = (float*)d_out;

    rank_partial_kernel<<<dim3(RT, RT), 256, 0, stream>>>(score0, score1, score2, partial);
    decode_scatter_kernel<<<RT, 256, 0, stream>>>(
        score0, bbox0, kps0, score1, bbox1, kps1, score2, bbox2, kps2,
        partial, s_logit, s_box, cnt, rowflag, out);
    pairs_kernel<<<NBP, 256, 0, stream>>>(s_logit, s_box, cnt, ent, diag, rowflag);
    nms_kernel<<<1, 256, 0, stream>>>(rowflag, cnt, diag, ent, out);
}